// Round 11
// baseline (136.853 us; speedup 1.0000x reference)
//
#include <hip/hip_runtime.h>
#include <float.h>
#include <limits.h>

#define BATCH 32
#define C_IN 16
#define C_OUT 32
#define NTOK 2048
#define KNN 3
#define ZH 2                  // m-halves per n
#define MSEG (NTOK / ZH)      // 1024 m per scan wave
#define WPB 4                 // waves per block (independent n-tiles)
#define HT (MSEG / 32)        // 32 tiles per stream (two streams per wave)

using f32x4v = __attribute__((ext_vector_type(4))) float;
using bf16x8 = __attribute__((ext_vector_type(8))) short;

__device__ __forceinline__ unsigned short f2bf(float f) {
    unsigned u = __float_as_uint(f);
    unsigned r = u + 0x7fffu + ((u >> 16) & 1u);   // RNE
    return (unsigned short)(r >> 16);
}
__device__ __forceinline__ float bf2f(unsigned short h) {
    return __uint_as_float(((unsigned)h) << 16);
}
__device__ __forceinline__ unsigned umin2(unsigned a, unsigned b) { return a < b ? a : b; }
__device__ __forceinline__ unsigned umax2(unsigned a, unsigned b) { return a > b ? a : b; }

// Kernel 1: per (b,n): sq (exact ref recipe), xTf fp32 column, Am bf16 hi/lo split.
// Am row layout (64 B): [hi c0..c15 | lo c0..c15] -> serves both A-frags and B-frags.
__global__ void __launch_bounds__(256) prep_kernel(
    const float* __restrict__ x, float* __restrict__ xTf,
    float* __restrict__ sqf, uint4* __restrict__ Am)
{
    const int n = blockIdx.x * 256 + threadIdx.x;
    const int b = blockIdx.y;
    const float* xb = x + (size_t)b * C_IN * NTOK;

    float v[C_IN];
#pragma unroll
    for (int c = 0; c < C_IN; ++c) v[c] = xb[(size_t)c * NTOK + n];

    float acc = 0.0f;
#pragma unroll
    for (int c = 0; c < C_IN; ++c) acc = __fadd_rn(acc, __fmul_rn(v[c], v[c]));
    sqf[(size_t)b * NTOK + n] = acc;

    float4* dst = (float4*)(xTf + ((size_t)b * NTOK + n) * C_IN);
#pragma unroll
    for (int j = 0; j < 4; ++j)
        dst[j] = make_float4(v[4*j+0], v[4*j+1], v[4*j+2], v[4*j+3]);

    unsigned hw[8], lw[8];
#pragma unroll
    for (int j = 0; j < 8; ++j) {
        const unsigned short h0 = f2bf(v[2*j]),   h1 = f2bf(v[2*j+1]);
        const unsigned short l0 = f2bf(v[2*j]   - bf2f(h0));
        const unsigned short l1 = f2bf(v[2*j+1] - bf2f(h1));
        hw[j] = (unsigned)h0 | ((unsigned)h1 << 16);
        lw[j] = (unsigned)l0 | ((unsigned)l1 << 16);
    }
    uint4* am = Am + ((size_t)b * NTOK + n) * 4;
    am[0] = make_uint4(hw[0], hw[1], hw[2], hw[3]);
    am[1] = make_uint4(hw[4], hw[5], hw[6], hw[7]);
    am[2] = make_uint4(lw[0], lw[1], lw[2], lw[3]);
    am[3] = make_uint4(lw[4], lw[5], lw[6], lw[7]);
}

// top-4 insert on packed sortable key, pure min/max chain
#define INS4(K0,K1,K2,K3,key) {                    \
    const unsigned o0 = K0, o1 = K1, o2 = K2;      \
    K0 = umin2(key, K0);                           \
    K1 = umin2(umax2(key, o0), K1);                \
    K2 = umin2(umax2(key, o1), K2);                \
    K3 = umin2(umax2(key, o2), K3); }

// Kernel 2: 256-thr block = 4 independent waves; wave w owns n-tile blockIdx.x*4+w,
// m-half z. TWO independent m-streams per wave (tiles t and t+HT): independent
// MFMA accumulators and two independent top-4 key lists -> halves the loop-carried
// serial insert chain. Per-lane 8 candidates (two disjoint 128-m subsets, top-4
// each); union of 4 lanes = 32 candidates/n; exact fp32 rescore; stable top-3.
__global__ void __launch_bounds__(256) knn_scan_kernel(
    const uint4* __restrict__ Am, const float* __restrict__ sqf,
    const float* __restrict__ xTf, float* __restrict__ pd, int* __restrict__ pi)
{
    __shared__ int   lds_ci[WPB][16][33];
    __shared__ float lds_de[WPB][16][33];

    const int tid  = threadIdx.x;
    const int w    = tid >> 6;
    const int l    = tid & 63;
    const int col  = l & 15;
    const int quad = l >> 4;
    const int nt = blockIdx.x * WPB + w;
    const int b  = blockIdx.y;
    const int z  = blockIdx.z;
    const int n  = nt * 16 + col;
    const int mbase = z * MSEG;

    const char*  amb = (const char*)Am + ((size_t)b * NTOK * 64);
    const float* sqb = sqf + (size_t)b * NTOK;

    // B-frags (n-side): lane holds k-chunk quad*8..+7 of B[k][col];
    // B = [y_hi|y_hi] resp. [y_lo|y_lo] -> chunk (quad&1) of hi resp. lo.
    const int koffB = (quad & 1) * 16;
    const bf16x8 Bhi = *(const bf16x8*)(amb + (size_t)n * 64 + koffB);
    const bf16x8 Blo = *(const bf16x8*)(amb + (size_t)n * 64 + 32 + koffB);

    unsigned kx0 = ~0u, kx1 = ~0u, kx2 = ~0u, kx3 = ~0u;   // stream X list
    unsigned ky0 = ~0u, ky1 = ~0u, ky2 = ~0u, ky3 = ~0u;   // stream Y list
    const int moff = quad * 4;

#pragma unroll 2
    for (int t = 0; t < HT; ++t) {
        const int mX = mbase + t * 16;
        const int mY = mbase + (t + HT) * 16;
        // A-frags for both streams (independent loads)
        const bf16x8 AfX = *(const bf16x8*)(amb + (size_t)(mX + col) * 64 + quad * 16);
        const bf16x8 AfY = *(const bf16x8*)(amb + (size_t)(mY + col) * 64 + quad * 16);
        const float4 sqX = *(const float4*)(sqb + mX + moff);
        const float4 sqY = *(const float4*)(sqb + mY + moff);

        f32x4v aX = {0.0f, 0.0f, 0.0f, 0.0f};
        f32x4v aY = {0.0f, 0.0f, 0.0f, 0.0f};
        aX = __builtin_amdgcn_mfma_f32_16x16x32_bf16(AfX, Bhi, aX, 0, 0, 0);
        aY = __builtin_amdgcn_mfma_f32_16x16x32_bf16(AfY, Bhi, aY, 0, 0, 0);
        aX = __builtin_amdgcn_mfma_f32_16x16x32_bf16(AfX, Blo, aX, 0, 0, 0);
        aY = __builtin_amdgcn_mfma_f32_16x16x32_bf16(AfY, Blo, aY, 0, 0, 0);

        const float sqaX[4] = { sqX.x, sqX.y, sqX.z, sqX.w };
        const float sqaY[4] = { sqY.x, sqY.y, sqY.z, sqY.w };
#pragma unroll
        for (int r = 0; r < 4; ++r) {
            // ranking distance (sqn dropped, monotone per n); sortable-uint key
            const float dX = __fmaf_rn(-2.0f, aX[r], sqaX[r]);
            const float dY = __fmaf_rn(-2.0f, aY[r], sqaY[r]);
            unsigned uX = __float_as_uint(dX);
            unsigned uY = __float_as_uint(dY);
            uX ^= (unsigned)((int)uX >> 31) | 0x80000000u;
            uY ^= (unsigned)((int)uY >> 31) | 0x80000000u;
            const unsigned keyX = (uX & 0xFFFFF800u) | (unsigned)(mX + moff + r);
            const unsigned keyY = (uY & 0xFFFFF800u) | (unsigned)(mY + moff + r);
            INS4(kx0, kx1, kx2, kx3, keyX);
            INS4(ky0, ky1, ky2, ky3, keyY);
        }
    }

    // dump 8 candidate indices per lane (decode global m from key)
    lds_ci[w][col][quad*8+0] = (int)(kx0 & 2047u);
    lds_ci[w][col][quad*8+1] = (int)(kx1 & 2047u);
    lds_ci[w][col][quad*8+2] = (int)(kx2 & 2047u);
    lds_ci[w][col][quad*8+3] = (int)(kx3 & 2047u);
    lds_ci[w][col][quad*8+4] = (int)(ky0 & 2047u);
    lds_ci[w][col][quad*8+5] = (int)(ky1 & 2047u);
    lds_ci[w][col][quad*8+6] = (int)(ky2 & 2047u);
    lds_ci[w][col][quad*8+7] = (int)(ky3 & 2047u);
    __syncthreads();

    // exact rescore: lane (col, quad) rescores candidates quad*8..+7 of n=col
    float xn[C_IN];
    {
        const float4* src = (const float4*)(xTf + ((size_t)b * NTOK + n) * C_IN);
#pragma unroll
        for (int j = 0; j < 4; ++j) {
            const float4 tq = src[j];
            xn[4*j+0] = tq.x; xn[4*j+1] = tq.y; xn[4*j+2] = tq.z; xn[4*j+3] = tq.w;
        }
    }
    const float sqn = sqb[n];
#pragma unroll
    for (int c = 0; c < 8; ++c) {
        const int cand = quad * 8 + c;
        const int mi = lds_ci[w][col][cand];
        const float4* xm4 = (const float4*)(xTf + ((size_t)b * NTOK + mi) * C_IN);
        const float4 a0 = xm4[0], a1 = xm4[1], a2 = xm4[2], a3 = xm4[3];
        float g = 0.0f;
        g = __fmaf_rn(xn[0],  a0.x, g); g = __fmaf_rn(xn[1],  a0.y, g);
        g = __fmaf_rn(xn[2],  a0.z, g); g = __fmaf_rn(xn[3],  a0.w, g);
        g = __fmaf_rn(xn[4],  a1.x, g); g = __fmaf_rn(xn[5],  a1.y, g);
        g = __fmaf_rn(xn[6],  a1.z, g); g = __fmaf_rn(xn[7],  a1.w, g);
        g = __fmaf_rn(xn[8],  a2.x, g); g = __fmaf_rn(xn[9],  a2.y, g);
        g = __fmaf_rn(xn[10], a2.z, g); g = __fmaf_rn(xn[11], a2.w, g);
        g = __fmaf_rn(xn[12], a3.x, g); g = __fmaf_rn(xn[13], a3.y, g);
        g = __fmaf_rn(xn[14], a3.z, g); g = __fmaf_rn(xn[15], a3.w, g);
        // exact (reference-rounded) distance
        lds_de[w][col][cand] = __fadd_rn(__fmaf_rn(-2.0f, g, sqn), sqb[mi]);
    }
    __syncthreads();

    // stable top-3 over 32 exact (d, idx): lexicographic, matches jax top_k ties
    if (l < 16) {
        float D0 = FLT_MAX, D1 = FLT_MAX, D2 = FLT_MAX;
        int   I0 = INT_MAX, I1 = INT_MAX, I2 = INT_MAX;
#pragma unroll
        for (int c = 0; c < 32; ++c) {
            const float d = lds_de[w][l][c];
            const int  ix = lds_ci[w][l][c];
            const bool b0 = (d < D0) || (d == D0 && ix < I0);
            const bool b1 = (d < D1) || (d == D1 && ix < I1);
            const bool b2 = (d < D2) || (d == D2 && ix < I2);
            const float oD0 = D0, oD1 = D1;
            const int   oI0 = I0, oI1 = I1;
            D0 = b0 ? d : D0;               I0 = b0 ? ix : I0;
            D1 = b0 ? oD0 : (b1 ? d : D1);  I1 = b0 ? oI0 : (b1 ? ix : I1);
            D2 = b1 ? oD1 : (b2 ? d : D2);  I2 = b1 ? oI1 : (b2 ? ix : I2);
        }
        // records: [((z*KNN + k)*BATCH + b)*NTOK + n]
        const size_t base = ((size_t)z * KNN * BATCH + b) * NTOK + nt * 16 + l;
        const size_t kstr = (size_t)BATCH * NTOK;
        pd[base + 0*kstr] = D0;  pi[base + 0*kstr] = I0;
        pd[base + 1*kstr] = D1;  pi[base + 1*kstr] = I1;
        pd[base + 2*kstr] = D2;  pi[base + 2*kstr] = I2;
    }
}

// Kernel 3: merge the 2 halves' exact top-3 (lexicographic on (d, m) == stable
// global top-3), gather 3 neighbor columns, conv epilogue.
__global__ void __launch_bounds__(256) merge_conv_kernel(
    const float* __restrict__ xTf, const float* __restrict__ pd,
    const int* __restrict__ pi, const float* __restrict__ W,
    const float* __restrict__ bias, float* __restrict__ out)
{
    const int n = blockIdx.x * 256 + threadIdx.x;
    const int b = blockIdx.y;

    float D0 = FLT_MAX, D1 = FLT_MAX, D2 = FLT_MAX;
    int   I0 = INT_MAX, I1 = INT_MAX, I2 = INT_MAX;
    const size_t kstr = (size_t)BATCH * NTOK;
#pragma unroll
    for (int z = 0; z < ZH; ++z) {
        const size_t base = ((size_t)z * KNN * BATCH + b) * NTOK + n;
#pragma unroll
        for (int k = 0; k < KNN; ++k) {
            const float d = pd[base + (size_t)k * kstr];
            const int  ix = pi[base + (size_t)k * kstr];
            const bool b0 = (d < D0) || (d == D0 && ix < I0);
            const bool b1 = (d < D1) || (d == D1 && ix < I1);
            const bool b2 = (d < D2) || (d == D2 && ix < I2);
            const float oD0 = D0, oD1 = D1;
            const int   oI0 = I0, oI1 = I1;
            D0 = b0 ? d : D0;               I0 = b0 ? ix : I0;
            D1 = b0 ? oD0 : (b1 ? d : D1);  I1 = b0 ? oI0 : (b1 ? ix : I1);
            D2 = b1 ? oD1 : (b2 ? d : D2);  I2 = b1 ? oI1 : (b2 ? ix : I2);
        }
    }

    const float* xb = xTf + (size_t)b * NTOK * C_IN;
    float xg[KNN][C_IN];
    const int idx[KNN] = { I0, I1, I2 };
#pragma unroll
    for (int k = 0; k < KNN; ++k) {
        const float4* src = (const float4*)(xb + (size_t)idx[k] * C_IN);
#pragma unroll
        for (int j = 0; j < 4; ++j) {
            const float4 t = src[j];
            xg[k][4*j+0] = t.x; xg[k][4*j+1] = t.y;
            xg[k][4*j+2] = t.z; xg[k][4*j+3] = t.w;
        }
    }

#pragma unroll
    for (int o = 0; o < C_OUT; ++o) {
        float acc = bias[o];
#pragma unroll
        for (int c = 0; c < C_IN; ++c) {
#pragma unroll
            for (int k = 0; k < KNN; ++k)
                acc = __fmaf_rn(W[(o * C_IN + c) * KNN + k], xg[k][c], acc);
        }
        out[((size_t)b * C_OUT + o) * NTOK + n] = acc;
    }
}

extern "C" void kernel_launch(void* const* d_in, const int* in_sizes, int n_in,
                              void* d_out, int out_size, void* d_ws, size_t ws_size,
                              hipStream_t stream) {
    const float* x    = (const float*)d_in[0];
    const float* W    = (const float*)d_in[1];
    const float* bias = (const float*)d_in[2];
    float* out = (float*)d_out;

    char* ws = (char*)d_ws;
    const size_t BN = (size_t)BATCH * NTOK;
    uint4* Am  = (uint4*)ws;                       // 4 MB
    float* sqf = (float*)(ws + BN * 64);           // 256 KB
    float* xTf = (float*)(ws + BN * 68);           // 4 MB
    float* pd  = (float*)(ws + BN * 68 + BN * 64); // ZH*KNN*BN*4 = 1.5 MB
    int*   pi  = (int*)  (ws + BN * 68 + BN * 64 + (size_t)ZH * KNN * BN * 4);

    dim3 grid1(NTOK / 256, BATCH);
    prep_kernel<<<grid1, 256, 0, stream>>>(x, xTf, sqf, Am);

    dim3 grid2(NTOK / (16 * WPB), BATCH, ZH);
    knn_scan_kernel<<<grid2, 256, 0, stream>>>(Am, sqf, xTf, pd, pi);

    dim3 grid3(NTOK / 256, BATCH);
    merge_conv_kernel<<<grid3, 256, 0, stream>>>(xTf, pd, pi, W, bias, out);
}

// Round 12
// 97.791 us; speedup vs baseline: 1.3994x; 1.3994x over previous
//
#include <hip/hip_runtime.h>
#include <float.h>
#include <limits.h>

#define BATCH 32
#define C_IN 16
#define C_OUT 32
#define NTOK 2048
#define KNN 3
#define ZH 2                  // m-halves per n
#define MSEG (NTOK / ZH)      // 1024 m per scan wave
#define WPB 4                 // waves per block (independent n-tiles)

using f32x4v = __attribute__((ext_vector_type(4))) float;
using bf16x8 = __attribute__((ext_vector_type(8))) short;

__device__ __forceinline__ unsigned short f2bf(float f) {
    unsigned u = __float_as_uint(f);
    unsigned r = u + 0x7fffu + ((u >> 16) & 1u);   // RNE
    return (unsigned short)(r >> 16);
}
__device__ __forceinline__ float bf2f(unsigned short h) {
    return __uint_as_float(((unsigned)h) << 16);
}
__device__ __forceinline__ unsigned umin2(unsigned a, unsigned b) { return a < b ? a : b; }
__device__ __forceinline__ unsigned umax2(unsigned a, unsigned b) { return a > b ? a : b; }

// Kernel 1: per (b,n): sq (exact ref recipe), xTf fp32 column, Am bf16 hi/lo split.
// Am row layout (64 B): [hi c0..c15 | lo c0..c15] -> serves both A-frags and B-frags.
__global__ void __launch_bounds__(256) prep_kernel(
    const float* __restrict__ x, float* __restrict__ xTf,
    float* __restrict__ sqf, uint4* __restrict__ Am)
{
    const int n = blockIdx.x * 256 + threadIdx.x;
    const int b = blockIdx.y;
    const float* xb = x + (size_t)b * C_IN * NTOK;

    float v[C_IN];
#pragma unroll
    for (int c = 0; c < C_IN; ++c) v[c] = xb[(size_t)c * NTOK + n];

    float acc = 0.0f;
#pragma unroll
    for (int c = 0; c < C_IN; ++c) acc = __fadd_rn(acc, __fmul_rn(v[c], v[c]));
    sqf[(size_t)b * NTOK + n] = acc;

    float4* dst = (float4*)(xTf + ((size_t)b * NTOK + n) * C_IN);
#pragma unroll
    for (int j = 0; j < 4; ++j)
        dst[j] = make_float4(v[4*j+0], v[4*j+1], v[4*j+2], v[4*j+3]);

    unsigned hw[8], lw[8];
#pragma unroll
    for (int j = 0; j < 8; ++j) {
        const unsigned short h0 = f2bf(v[2*j]),   h1 = f2bf(v[2*j+1]);
        const unsigned short l0 = f2bf(v[2*j]   - bf2f(h0));
        const unsigned short l1 = f2bf(v[2*j+1] - bf2f(h1));
        hw[j] = (unsigned)h0 | ((unsigned)h1 << 16);
        lw[j] = (unsigned)l0 | ((unsigned)l1 << 16);
    }
    uint4* am = Am + ((size_t)b * NTOK + n) * 4;
    am[0] = make_uint4(hw[0], hw[1], hw[2], hw[3]);
    am[1] = make_uint4(hw[4], hw[5], hw[6], hw[7]);
    am[2] = make_uint4(lw[0], lw[1], lw[2], lw[3]);
    am[3] = make_uint4(lw[4], lw[5], lw[6], lw[7]);
}

// Kernel 2: R10 structure (proven 81.7 us) + XCD-aware b-locality swizzle.
// 1-D grid, wgid = (b%8) + 8*((b/8)*64 + z*32 + ntb): HW round-robins
// consecutive wgids across the 8 XCDs -> XCD k serves only b = k (mod 8)
// (4 batches -> Am+xTf working set ~1.6 MB << 4 MB L2, vs 12 MB unswizzled).
__global__ void __launch_bounds__(256) knn_scan_kernel(
    const uint4* __restrict__ Am, const float* __restrict__ sqf,
    const float* __restrict__ xTf, float* __restrict__ pd, int* __restrict__ pi)
{
    __shared__ int   lds_ci[WPB][16][17];
    __shared__ float lds_de[WPB][16][17];

    const int tid  = threadIdx.x;
    const int w    = tid >> 6;
    const int l    = tid & 63;
    const int col  = l & 15;
    const int quad = l >> 4;

    // decode swizzled block coords
    const int wg   = blockIdx.x;        // 0..2047
    const int b_lo = wg & 7;
    const int t2   = wg >> 3;           // 0..255
    const int b_hi = t2 >> 6;           // 0..3
    const int rest = t2 & 63;
    const int z    = rest >> 5;         // 0..1
    const int ntb  = rest & 31;         // 0..31
    const int b    = b_lo + (b_hi << 3);
    const int nt   = ntb * WPB + w;

    const int n  = nt * 16 + col;
    const int mbase = z * MSEG;

    const char*  amb = (const char*)Am + ((size_t)b * NTOK * 64);
    const float* sqb = sqf + (size_t)b * NTOK;

    // B-frags (n-side): lane holds k-chunk quad*8..+7 of B[k][col];
    // B = [y_hi|y_hi] resp. [y_lo|y_lo] -> chunk (quad&1) of hi resp. lo.
    const int koffB = (quad & 1) * 16;
    const bf16x8 Bhi = *(const bf16x8*)(amb + (size_t)n * 64 + koffB);
    const bf16x8 Blo = *(const bf16x8*)(amb + (size_t)n * 64 + 32 + koffB);

    unsigned k0 = ~0u, k1 = ~0u, k2 = ~0u, k3 = ~0u;
    const int moff = quad * 4;

#pragma unroll 2
    for (int t = 0; t < MSEG / 16; ++t) {
        // A-frag (m-side): lane row = col, k-chunk = quad -> Am row bytes quad*16
        const bf16x8 Af = *(const bf16x8*)(amb + (size_t)(mbase + t * 16 + col) * 64 + quad * 16);
        const float4 sq4 = *(const float4*)(sqb + mbase + t * 16 + moff);

        f32x4v acc = {0.0f, 0.0f, 0.0f, 0.0f};
        acc = __builtin_amdgcn_mfma_f32_16x16x32_bf16(Af, Bhi, acc, 0, 0, 0);
        acc = __builtin_amdgcn_mfma_f32_16x16x32_bf16(Af, Blo, acc, 0, 0, 0);

        const int mb = mbase + t * 16 + moff;
        const float sqa[4] = { sq4.x, sq4.y, sq4.z, sq4.w };
#pragma unroll
        for (int r = 0; r < 4; ++r) {
            // ranking distance: sqn dropped (monotone per n)
            const float d = __fmaf_rn(-2.0f, acc[r], sqa[r]);
            // sortable-uint transform (ascending) + pack global m into low 11 bits
            unsigned u = __float_as_uint(d);
            u ^= (unsigned)((int)u >> 31) | 0x80000000u;
            const unsigned key = (u & 0xFFFFF800u) | (unsigned)(mb + r);
            // top-4 insert, pure min/max chain (no index bookkeeping)
            const unsigned ok0 = k0, ok1 = k1, ok2 = k2;
            k0 = umin2(key, k0);
            k1 = umin2(umax2(key, ok0), k1);
            k2 = umin2(umax2(key, ok1), k2);
            k3 = umin2(umax2(key, ok2), k3);
        }
    }

    // dump 4 candidate indices per lane (decode global m from key)
    lds_ci[w][col][quad*4+0] = (int)(k0 & 2047u);
    lds_ci[w][col][quad*4+1] = (int)(k1 & 2047u);
    lds_ci[w][col][quad*4+2] = (int)(k2 & 2047u);
    lds_ci[w][col][quad*4+3] = (int)(k3 & 2047u);
    __syncthreads();

    // exact rescore: lane (col, quad) rescores candidates quad*4..+3 of n=col
    float xn[C_IN];
    {
        const float4* src = (const float4*)(xTf + ((size_t)b * NTOK + n) * C_IN);
#pragma unroll
        for (int j = 0; j < 4; ++j) {
            const float4 tq = src[j];
            xn[4*j+0] = tq.x; xn[4*j+1] = tq.y; xn[4*j+2] = tq.z; xn[4*j+3] = tq.w;
        }
    }
    const float sqn = sqb[n];
#pragma unroll
    for (int c = 0; c < 4; ++c) {
        const int cand = quad * 4 + c;
        const int mi = lds_ci[w][col][cand];
        const float4* xm4 = (const float4*)(xTf + ((size_t)b * NTOK + mi) * C_IN);
        const float4 a0 = xm4[0], a1 = xm4[1], a2 = xm4[2], a3 = xm4[3];
        float g = 0.0f;
        g = __fmaf_rn(xn[0],  a0.x, g); g = __fmaf_rn(xn[1],  a0.y, g);
        g = __fmaf_rn(xn[2],  a0.z, g); g = __fmaf_rn(xn[3],  a0.w, g);
        g = __fmaf_rn(xn[4],  a1.x, g); g = __fmaf_rn(xn[5],  a1.y, g);
        g = __fmaf_rn(xn[6],  a1.z, g); g = __fmaf_rn(xn[7],  a1.w, g);
        g = __fmaf_rn(xn[8],  a2.x, g); g = __fmaf_rn(xn[9],  a2.y, g);
        g = __fmaf_rn(xn[10], a2.z, g); g = __fmaf_rn(xn[11], a2.w, g);
        g = __fmaf_rn(xn[12], a3.x, g); g = __fmaf_rn(xn[13], a3.y, g);
        g = __fmaf_rn(xn[14], a3.z, g); g = __fmaf_rn(xn[15], a3.w, g);
        // exact (reference-rounded) distance
        lds_de[w][col][cand] = __fadd_rn(__fmaf_rn(-2.0f, g, sqn), sqb[mi]);
    }
    __syncthreads();

    // stable top-3 over 16 exact (d, idx): lexicographic, matches jax top_k ties
    if (l < 16) {
        float D0 = FLT_MAX, D1 = FLT_MAX, D2 = FLT_MAX;
        int   I0 = INT_MAX, I1 = INT_MAX, I2 = INT_MAX;
#pragma unroll
        for (int c = 0; c < 16; ++c) {
            const float d = lds_de[w][l][c];
            const int  ix = lds_ci[w][l][c];
            const bool b0 = (d < D0) || (d == D0 && ix < I0);
            const bool b1 = (d < D1) || (d == D1 && ix < I1);
            const bool b2 = (d < D2) || (d == D2 && ix < I2);
            const float oD0 = D0, oD1 = D1;
            const int   oI0 = I0, oI1 = I1;
            D0 = b0 ? d : D0;               I0 = b0 ? ix : I0;
            D1 = b0 ? oD0 : (b1 ? d : D1);  I1 = b0 ? oI0 : (b1 ? ix : I1);
            D2 = b1 ? oD1 : (b2 ? d : D2);  I2 = b1 ? oI1 : (b2 ? ix : I2);
        }
        // records: [((z*KNN + k)*BATCH + b)*NTOK + n]
        const size_t base = ((size_t)z * KNN * BATCH + b) * NTOK + nt * 16 + l;
        const size_t kstr = (size_t)BATCH * NTOK;
        pd[base + 0*kstr] = D0;  pi[base + 0*kstr] = I0;
        pd[base + 1*kstr] = D1;  pi[base + 1*kstr] = I1;
        pd[base + 2*kstr] = D2;  pi[base + 2*kstr] = I2;
    }
}

// Kernel 3: merge the 2 halves' exact top-3 (lexicographic on (d, m) == stable
// global top-3), gather 3 neighbor columns, conv epilogue. Same b-locality swizzle.
__global__ void __launch_bounds__(256) merge_conv_kernel(
    const float* __restrict__ xTf, const float* __restrict__ pd,
    const int* __restrict__ pi, const float* __restrict__ W,
    const float* __restrict__ bias, float* __restrict__ out)
{
    // decode swizzled block coords: wg = (b%8) + 8*((b/8)*8 + xc), 256 blocks
    const int wg   = blockIdx.x;        // 0..255
    const int b_lo = wg & 7;
    const int t2   = wg >> 3;           // 0..31
    const int b_hi = t2 >> 3;           // 0..3
    const int xc   = t2 & 7;            // 0..7
    const int b    = b_lo + (b_hi << 3);
    const int n    = xc * 256 + threadIdx.x;

    float D0 = FLT_MAX, D1 = FLT_MAX, D2 = FLT_MAX;
    int   I0 = INT_MAX, I1 = INT_MAX, I2 = INT_MAX;
    const size_t kstr = (size_t)BATCH * NTOK;
#pragma unroll
    for (int z = 0; z < ZH; ++z) {
        const size_t base = ((size_t)z * KNN * BATCH + b) * NTOK + n;
#pragma unroll
        for (int k = 0; k < KNN; ++k) {
            const float d = pd[base + (size_t)k * kstr];
            const int  ix = pi[base + (size_t)k * kstr];
            const bool b0 = (d < D0) || (d == D0 && ix < I0);
            const bool b1 = (d < D1) || (d == D1 && ix < I1);
            const bool b2 = (d < D2) || (d == D2 && ix < I2);
            const float oD0 = D0, oD1 = D1;
            const int   oI0 = I0, oI1 = I1;
            D0 = b0 ? d : D0;               I0 = b0 ? ix : I0;
            D1 = b0 ? oD0 : (b1 ? d : D1);  I1 = b0 ? oI0 : (b1 ? ix : I1);
            D2 = b1 ? oD1 : (b2 ? d : D2);  I2 = b1 ? oI1 : (b2 ? ix : I2);
        }
    }

    const float* xb = xTf + (size_t)b * NTOK * C_IN;
    float xg[KNN][C_IN];
    const int idx[KNN] = { I0, I1, I2 };
#pragma unroll
    for (int k = 0; k < KNN; ++k) {
        const float4* src = (const float4*)(xb + (size_t)idx[k] * C_IN);
#pragma unroll
        for (int j = 0; j < 4; ++j) {
            const float4 t = src[j];
            xg[k][4*j+0] = t.x; xg[k][4*j+1] = t.y;
            xg[k][4*j+2] = t.z; xg[k][4*j+3] = t.w;
        }
    }

#pragma unroll
    for (int o = 0; o < C_OUT; ++o) {
        float acc = bias[o];
#pragma unroll
        for (int c = 0; c < C_IN; ++c) {
#pragma unroll
            for (int k = 0; k < KNN; ++k)
                acc = __fmaf_rn(W[(o * C_IN + c) * KNN + k], xg[k][c], acc);
        }
        out[((size_t)b * C_OUT + o) * NTOK + n] = acc;
    }
}

extern "C" void kernel_launch(void* const* d_in, const int* in_sizes, int n_in,
                              void* d_out, int out_size, void* d_ws, size_t ws_size,
                              hipStream_t stream) {
    const float* x    = (const float*)d_in[0];
    const float* W    = (const float*)d_in[1];
    const float* bias = (const float*)d_in[2];
    float* out = (float*)d_out;

    char* ws = (char*)d_ws;
    const size_t BN = (size_t)BATCH * NTOK;
    uint4* Am  = (uint4*)ws;                       // 4 MB
    float* sqf = (float*)(ws + BN * 64);           // 256 KB
    float* xTf = (float*)(ws + BN * 68);           // 4 MB
    float* pd  = (float*)(ws + BN * 68 + BN * 64); // ZH*KNN*BN*4 = 1.5 MB
    int*   pi  = (int*)  (ws + BN * 68 + BN * 64 + (size_t)ZH * KNN * BN * 4);

    dim3 grid1(NTOK / 256, BATCH);
    prep_kernel<<<grid1, 256, 0, stream>>>(x, xTf, sqf, Am);

    // 2048 blocks, 1-D, XCD-swizzled
    knn_scan_kernel<<<dim3(BATCH * (NTOK / (16 * WPB)) * ZH), 256, 0, stream>>>(Am, sqf, xTf, pd, pi);

    // 256 blocks, 1-D, XCD-swizzled
    merge_conv_kernel<<<dim3(BATCH * (NTOK / 256)), 256, 0, stream>>>(xTf, pd, pi, W, bias, out);
}

// Round 13
// 93.374 us; speedup vs baseline: 1.4656x; 1.0473x over previous
//
#include <hip/hip_runtime.h>
#include <float.h>
#include <limits.h>

#define BATCH 32
#define C_IN 16
#define C_OUT 32
#define NTOK 2048
#define KNN 3
#define ZH 2                  // m-halves per n
#define MSEG (NTOK / ZH)      // 1024 m per scan wave
#define WPB 4                 // waves per block (independent n-tiles)

using f32x4v = __attribute__((ext_vector_type(4))) float;
using bf16x8 = __attribute__((ext_vector_type(8))) short;

__device__ __forceinline__ unsigned short f2bf(float f) {
    unsigned u = __float_as_uint(f);
    unsigned r = u + 0x7fffu + ((u >> 16) & 1u);   // RNE
    return (unsigned short)(r >> 16);
}
__device__ __forceinline__ float bf2f(unsigned short h) {
    return __uint_as_float(((unsigned)h) << 16);
}
__device__ __forceinline__ unsigned umin2(unsigned a, unsigned b) { return a < b ? a : b; }
__device__ __forceinline__ unsigned umax2(unsigned a, unsigned b) { return a > b ? a : b; }

// Kernel 1: per (b,n): sq (exact ref recipe), xTf fp32 column, Am bf16 hi/lo split.
// Am layout: FRAGMENT-TILE-INTERLEAVED. For 16-row tile nt, uint4 index
// nt*64 + q*16 + col holds k-chunk q (0,1 = hi; 2,3 = lo) of row nt*16+col.
// => scan's A-fragment load is base + (tile*64 + lane)*16: perfectly coalesced.
__global__ void __launch_bounds__(256) prep_kernel(
    const float* __restrict__ x, float* __restrict__ xTf,
    float* __restrict__ sqf, uint4* __restrict__ Am)
{
    const int n = blockIdx.x * 256 + threadIdx.x;
    const int b = blockIdx.y;
    const float* xb = x + (size_t)b * C_IN * NTOK;

    float v[C_IN];
#pragma unroll
    for (int c = 0; c < C_IN; ++c) v[c] = xb[(size_t)c * NTOK + n];

    float acc = 0.0f;
#pragma unroll
    for (int c = 0; c < C_IN; ++c) acc = __fadd_rn(acc, __fmul_rn(v[c], v[c]));
    sqf[(size_t)b * NTOK + n] = acc;

    float4* dst = (float4*)(xTf + ((size_t)b * NTOK + n) * C_IN);
#pragma unroll
    for (int j = 0; j < 4; ++j)
        dst[j] = make_float4(v[4*j+0], v[4*j+1], v[4*j+2], v[4*j+3]);

    unsigned hw[8], lw[8];
#pragma unroll
    for (int j = 0; j < 8; ++j) {
        const unsigned short h0 = f2bf(v[2*j]),   h1 = f2bf(v[2*j+1]);
        const unsigned short l0 = f2bf(v[2*j]   - bf2f(h0));
        const unsigned short l1 = f2bf(v[2*j+1] - bf2f(h1));
        hw[j] = (unsigned)h0 | ((unsigned)h1 << 16);
        lw[j] = (unsigned)l0 | ((unsigned)l1 << 16);
    }
    uint4* amb = Am + (size_t)b * NTOK * 4;
    const int nt  = n >> 4;
    const int col = n & 15;
    amb[nt*64 + 0*16 + col] = make_uint4(hw[0], hw[1], hw[2], hw[3]);  // hi chunk0
    amb[nt*64 + 1*16 + col] = make_uint4(hw[4], hw[5], hw[6], hw[7]);  // hi chunk1
    amb[nt*64 + 2*16 + col] = make_uint4(lw[0], lw[1], lw[2], lw[3]);  // lo chunk0
    amb[nt*64 + 3*16 + col] = make_uint4(lw[4], lw[5], lw[6], lw[7]);  // lo chunk1
}

// Kernel 2: R12 structure + XCD b-locality swizzle + fragment-interleaved A loads.
__global__ void __launch_bounds__(256) knn_scan_kernel(
    const uint4* __restrict__ Am, const float* __restrict__ sqf,
    const float* __restrict__ xTf, float* __restrict__ pd, int* __restrict__ pi)
{
    __shared__ int   lds_ci[WPB][16][17];
    __shared__ float lds_de[WPB][16][17];

    const int tid  = threadIdx.x;
    const int w    = tid >> 6;
    const int l    = tid & 63;
    const int col  = l & 15;
    const int quad = l >> 4;

    // decode swizzled block coords: wgid = (b%8) + 8*((b/8)*64 + z*32 + ntb)
    const int wg   = blockIdx.x;        // 0..2047
    const int b_lo = wg & 7;
    const int t2   = wg >> 3;           // 0..255
    const int b_hi = t2 >> 6;           // 0..3
    const int rest = t2 & 63;
    const int z    = rest >> 5;         // 0..1
    const int ntb  = rest & 31;         // 0..31
    const int b    = b_lo + (b_hi << 3);
    const int nt   = ntb * WPB + w;

    const int n  = nt * 16 + col;
    const int mbase = z * MSEG;

    const uint4* amb = Am + (size_t)b * NTOK * 4;
    const float* sqb = sqf + (size_t)b * NTOK;

    // B-frags from interleaved layout: lane needs chunk (quad&1) of hi (Bhi)
    // and chunk (quad&1) of lo (Blo) of row n -> tile nt, positions
    // (quad&1)*16+col and (2+(quad&1))*16+col.
    const uint4 bh4 = amb[(size_t)nt*64 + ((quad & 1) * 16) + col];
    const uint4 bl4 = amb[(size_t)nt*64 + ((2 + (quad & 1)) * 16) + col];
    const bf16x8 Bhi = *(const bf16x8*)&bh4;
    const bf16x8 Blo = *(const bf16x8*)&bl4;

    unsigned k0 = ~0u, k1 = ~0u, k2 = ~0u, k3 = ~0u;
    const int moff = quad * 4;
    const int tgbase = z * (MSEG / 16);   // global tile base for this half

#pragma unroll 2
    for (int t = 0; t < MSEG / 16; ++t) {
        // A-frag: contiguous 1 KB tile, lane l reads element l (coalesced)
        const uint4 af4 = amb[(size_t)(tgbase + t) * 64 + l];
        const bf16x8 Af = *(const bf16x8*)&af4;
        const float4 sq4 = *(const float4*)(sqb + mbase + t * 16 + moff);

        f32x4v acc = {0.0f, 0.0f, 0.0f, 0.0f};
        acc = __builtin_amdgcn_mfma_f32_16x16x32_bf16(Af, Bhi, acc, 0, 0, 0);
        acc = __builtin_amdgcn_mfma_f32_16x16x32_bf16(Af, Blo, acc, 0, 0, 0);

        const int mb = mbase + t * 16 + moff;
        const float sqa[4] = { sq4.x, sq4.y, sq4.z, sq4.w };
#pragma unroll
        for (int r = 0; r < 4; ++r) {
            // ranking distance: sqn dropped (monotone per n)
            const float d = __fmaf_rn(-2.0f, acc[r], sqa[r]);
            // sortable-uint transform (ascending) + pack global m into low 11 bits
            unsigned u = __float_as_uint(d);
            u ^= (unsigned)((int)u >> 31) | 0x80000000u;
            const unsigned key = (u & 0xFFFFF800u) | (unsigned)(mb + r);
            // top-4 insert, pure min/max chain (no index bookkeeping)
            const unsigned ok0 = k0, ok1 = k1, ok2 = k2;
            k0 = umin2(key, k0);
            k1 = umin2(umax2(key, ok0), k1);
            k2 = umin2(umax2(key, ok1), k2);
            k3 = umin2(umax2(key, ok2), k3);
        }
    }

    // dump 4 candidate indices per lane (decode global m from key)
    lds_ci[w][col][quad*4+0] = (int)(k0 & 2047u);
    lds_ci[w][col][quad*4+1] = (int)(k1 & 2047u);
    lds_ci[w][col][quad*4+2] = (int)(k2 & 2047u);
    lds_ci[w][col][quad*4+3] = (int)(k3 & 2047u);
    __syncthreads();

    // exact rescore: lane (col, quad) rescores candidates quad*4..+3 of n=col
    float xn[C_IN];
    {
        const float4* src = (const float4*)(xTf + ((size_t)b * NTOK + n) * C_IN);
#pragma unroll
        for (int j = 0; j < 4; ++j) {
            const float4 tq = src[j];
            xn[4*j+0] = tq.x; xn[4*j+1] = tq.y; xn[4*j+2] = tq.z; xn[4*j+3] = tq.w;
        }
    }
    const float sqn = sqb[n];
#pragma unroll
    for (int c = 0; c < 4; ++c) {
        const int cand = quad * 4 + c;
        const int mi = lds_ci[w][col][cand];
        const float4* xm4 = (const float4*)(xTf + ((size_t)b * NTOK + mi) * C_IN);
        const float4 a0 = xm4[0], a1 = xm4[1], a2 = xm4[2], a3 = xm4[3];
        float g = 0.0f;
        g = __fmaf_rn(xn[0],  a0.x, g); g = __fmaf_rn(xn[1],  a0.y, g);
        g = __fmaf_rn(xn[2],  a0.z, g); g = __fmaf_rn(xn[3],  a0.w, g);
        g = __fmaf_rn(xn[4],  a1.x, g); g = __fmaf_rn(xn[5],  a1.y, g);
        g = __fmaf_rn(xn[6],  a1.z, g); g = __fmaf_rn(xn[7],  a1.w, g);
        g = __fmaf_rn(xn[8],  a2.x, g); g = __fmaf_rn(xn[9],  a2.y, g);
        g = __fmaf_rn(xn[10], a2.z, g); g = __fmaf_rn(xn[11], a2.w, g);
        g = __fmaf_rn(xn[12], a3.x, g); g = __fmaf_rn(xn[13], a3.y, g);
        g = __fmaf_rn(xn[14], a3.z, g); g = __fmaf_rn(xn[15], a3.w, g);
        // exact (reference-rounded) distance
        lds_de[w][col][cand] = __fadd_rn(__fmaf_rn(-2.0f, g, sqn), sqb[mi]);
    }
    __syncthreads();

    // stable top-3 over 16 exact (d, idx): lexicographic, matches jax top_k ties
    if (l < 16) {
        float D0 = FLT_MAX, D1 = FLT_MAX, D2 = FLT_MAX;
        int   I0 = INT_MAX, I1 = INT_MAX, I2 = INT_MAX;
#pragma unroll
        for (int c = 0; c < 16; ++c) {
            const float d = lds_de[w][l][c];
            const int  ix = lds_ci[w][l][c];
            const bool b0 = (d < D0) || (d == D0 && ix < I0);
            const bool b1 = (d < D1) || (d == D1 && ix < I1);
            const bool b2 = (d < D2) || (d == D2 && ix < I2);
            const float oD0 = D0, oD1 = D1;
            const int   oI0 = I0, oI1 = I1;
            D0 = b0 ? d : D0;               I0 = b0 ? ix : I0;
            D1 = b0 ? oD0 : (b1 ? d : D1);  I1 = b0 ? oI0 : (b1 ? ix : I1);
            D2 = b1 ? oD1 : (b2 ? d : D2);  I2 = b1 ? oI1 : (b2 ? ix : I2);
        }
        // records: [((z*KNN + k)*BATCH + b)*NTOK + n]
        const size_t base = ((size_t)z * KNN * BATCH + b) * NTOK + nt * 16 + l;
        const size_t kstr = (size_t)BATCH * NTOK;
        pd[base + 0*kstr] = D0;  pi[base + 0*kstr] = I0;
        pd[base + 1*kstr] = D1;  pi[base + 1*kstr] = I1;
        pd[base + 2*kstr] = D2;  pi[base + 2*kstr] = I2;
    }
}

// Kernel 3: merge the 2 halves' exact top-3 (lexicographic on (d, m) == stable
// global top-3), gather 3 neighbor columns, conv epilogue. Same b-locality swizzle.
__global__ void __launch_bounds__(256) merge_conv_kernel(
    const float* __restrict__ xTf, const float* __restrict__ pd,
    const int* __restrict__ pi, const float* __restrict__ W,
    const float* __restrict__ bias, float* __restrict__ out)
{
    // decode swizzled block coords: wg = (b%8) + 8*((b/8)*8 + xc), 256 blocks
    const int wg   = blockIdx.x;        // 0..255
    const int b_lo = wg & 7;
    const int t2   = wg >> 3;           // 0..31
    const int b_hi = t2 >> 3;           // 0..3
    const int xc   = t2 & 7;            // 0..7
    const int b    = b_lo + (b_hi << 3);
    const int n    = xc * 256 + threadIdx.x;

    float D0 = FLT_MAX, D1 = FLT_MAX, D2 = FLT_MAX;
    int   I0 = INT_MAX, I1 = INT_MAX, I2 = INT_MAX;
    const size_t kstr = (size_t)BATCH * NTOK;
#pragma unroll
    for (int z = 0; z < ZH; ++z) {
        const size_t base = ((size_t)z * KNN * BATCH + b) * NTOK + n;
#pragma unroll
        for (int k = 0; k < KNN; ++k) {
            const float d = pd[base + (size_t)k * kstr];
            const int  ix = pi[base + (size_t)k * kstr];
            const bool b0 = (d < D0) || (d == D0 && ix < I0);
            const bool b1 = (d < D1) || (d == D1 && ix < I1);
            const bool b2 = (d < D2) || (d == D2 && ix < I2);
            const float oD0 = D0, oD1 = D1;
            const int   oI0 = I0, oI1 = I1;
            D0 = b0 ? d : D0;               I0 = b0 ? ix : I0;
            D1 = b0 ? oD0 : (b1 ? d : D1);  I1 = b0 ? oI0 : (b1 ? ix : I1);
            D2 = b1 ? oD1 : (b2 ? d : D2);  I2 = b1 ? oI1 : (b2 ? ix : I2);
        }
    }

    const float* xb = xTf + (size_t)b * NTOK * C_IN;
    float xg[KNN][C_IN];
    const int idx[KNN] = { I0, I1, I2 };
#pragma unroll
    for (int k = 0; k < KNN; ++k) {
        const float4* src = (const float4*)(xb + (size_t)idx[k] * C_IN);
#pragma unroll
        for (int j = 0; j < 4; ++j) {
            const float4 t = src[j];
            xg[k][4*j+0] = t.x; xg[k][4*j+1] = t.y;
            xg[k][4*j+2] = t.z; xg[k][4*j+3] = t.w;
        }
    }

#pragma unroll
    for (int o = 0; o < C_OUT; ++o) {
        float acc = bias[o];
#pragma unroll
        for (int c = 0; c < C_IN; ++c) {
#pragma unroll
            for (int k = 0; k < KNN; ++k)
                acc = __fmaf_rn(W[(o * C_IN + c) * KNN + k], xg[k][c], acc);
        }
        out[((size_t)b * C_OUT + o) * NTOK + n] = acc;
    }
}

extern "C" void kernel_launch(void* const* d_in, const int* in_sizes, int n_in,
                              void* d_out, int out_size, void* d_ws, size_t ws_size,
                              hipStream_t stream) {
    const float* x    = (const float*)d_in[0];
    const float* W    = (const float*)d_in[1];
    const float* bias = (const float*)d_in[2];
    float* out = (float*)d_out;

    char* ws = (char*)d_ws;
    const size_t BN = (size_t)BATCH * NTOK;
    uint4* Am  = (uint4*)ws;                       // 4 MB
    float* sqf = (float*)(ws + BN * 64);           // 256 KB
    float* xTf = (float*)(ws + BN * 68);           // 4 MB
    float* pd  = (float*)(ws + BN * 68 + BN * 64); // ZH*KNN*BN*4 = 1.5 MB
    int*   pi  = (int*)  (ws + BN * 68 + BN * 64 + (size_t)ZH * KNN * BN * 4);

    dim3 grid1(NTOK / 256, BATCH);
    prep_kernel<<<grid1, 256, 0, stream>>>(x, xTf, sqf, Am);

    // 2048 blocks, 1-D, XCD-swizzled
    knn_scan_kernel<<<dim3(BATCH * (NTOK / (16 * WPB)) * ZH), 256, 0, stream>>>(Am, sqf, xTf, pd, pi);

    // 256 blocks, 1-D, XCD-swizzled
    merge_conv_kernel<<<dim3(BATCH * (NTOK / 256)), 256, 0, stream>>>(xTf, pd, pi, W, bias, out);
}

// Round 14
// 79.155 us; speedup vs baseline: 1.7289x; 1.1796x over previous
//
#include <hip/hip_runtime.h>
#include <float.h>
#include <limits.h>

#define BATCH 32
#define C_IN 16
#define C_OUT 32
#define NTOK 2048
#define KNN 3
#define ZH 2                  // m-halves per n
#define MSEG (NTOK / ZH)      // 1024 m per scan wave
#define WPB 4                 // waves per block (independent n-tiles)

using f32x4v = __attribute__((ext_vector_type(4))) float;
using bf16x8 = __attribute__((ext_vector_type(8))) short;

__device__ __forceinline__ unsigned short f2bf(float f) {
    unsigned u = __float_as_uint(f);
    unsigned r = u + 0x7fffu + ((u >> 16) & 1u);   // RNE
    return (unsigned short)(r >> 16);
}
__device__ __forceinline__ float bf2f(unsigned short h) {
    return __uint_as_float(((unsigned)h) << 16);
}
__device__ __forceinline__ unsigned umin2(unsigned a, unsigned b) { return a < b ? a : b; }
__device__ __forceinline__ unsigned med3u(unsigned a, unsigned b, unsigned c) {
    unsigned d;
    asm("v_med3_u32 %0, %1, %2, %3" : "=v"(d) : "v"(a), "v"(b), "v"(c));
    return d;
}

// Kernel 1: per (b,n): sq (exact ref recipe), xTf fp32 column, Am bf16 hi/lo split.
// Am layout: FRAGMENT-TILE-INTERLEAVED (R13). For 16-row tile nt, uint4 index
// nt*64 + q*16 + col holds k-chunk q (0,1 = hi; 2,3 = lo) of row nt*16+col.
__global__ void __launch_bounds__(256) prep_kernel(
    const float* __restrict__ x, float* __restrict__ xTf,
    float* __restrict__ sqf, uint4* __restrict__ Am)
{
    const int n = blockIdx.x * 256 + threadIdx.x;
    const int b = blockIdx.y;
    const float* xb = x + (size_t)b * C_IN * NTOK;

    float v[C_IN];
#pragma unroll
    for (int c = 0; c < C_IN; ++c) v[c] = xb[(size_t)c * NTOK + n];

    float acc = 0.0f;
#pragma unroll
    for (int c = 0; c < C_IN; ++c) acc = __fadd_rn(acc, __fmul_rn(v[c], v[c]));
    sqf[(size_t)b * NTOK + n] = acc;

    float4* dst = (float4*)(xTf + ((size_t)b * NTOK + n) * C_IN);
#pragma unroll
    for (int j = 0; j < 4; ++j)
        dst[j] = make_float4(v[4*j+0], v[4*j+1], v[4*j+2], v[4*j+3]);

    unsigned hw[8], lw[8];
#pragma unroll
    for (int j = 0; j < 8; ++j) {
        const unsigned short h0 = f2bf(v[2*j]),   h1 = f2bf(v[2*j+1]);
        const unsigned short l0 = f2bf(v[2*j]   - bf2f(h0));
        const unsigned short l1 = f2bf(v[2*j+1] - bf2f(h1));
        hw[j] = (unsigned)h0 | ((unsigned)h1 << 16);
        lw[j] = (unsigned)l0 | ((unsigned)l1 << 16);
    }
    uint4* amb = Am + (size_t)b * NTOK * 4;
    const int nt  = n >> 4;
    const int col = n & 15;
    amb[nt*64 + 0*16 + col] = make_uint4(hw[0], hw[1], hw[2], hw[3]);  // hi chunk0
    amb[nt*64 + 1*16 + col] = make_uint4(hw[4], hw[5], hw[6], hw[7]);  // hi chunk1
    amb[nt*64 + 2*16 + col] = make_uint4(lw[0], lw[1], lw[2], lw[3]);  // lo chunk0
    amb[nt*64 + 3*16 + col] = make_uint4(lw[4], lw[5], lw[6], lw[7]);  // lo chunk1
}

// Kernel 2: R13 structure; inner loop thinned: positive-bias uint key (no
// sign-flip transform) + v_med3_u32 sorted-top-4 insert (min + 3 med3).
__global__ void __launch_bounds__(256) knn_scan_kernel(
    const uint4* __restrict__ Am, const float* __restrict__ sqf,
    const float* __restrict__ xTf, float* __restrict__ pd, int* __restrict__ pi)
{
    __shared__ int   lds_ci[WPB][16][17];
    __shared__ float lds_de[WPB][16][17];

    const int tid  = threadIdx.x;
    const int w    = tid >> 6;
    const int l    = tid & 63;
    const int col  = l & 15;
    const int quad = l >> 4;

    // decode swizzled block coords: wgid = (b%8) + 8*((b/8)*64 + z*32 + ntb)
    const int wg   = blockIdx.x;        // 0..2047
    const int b_lo = wg & 7;
    const int t2   = wg >> 3;           // 0..255
    const int b_hi = t2 >> 6;           // 0..3
    const int rest = t2 & 63;
    const int z    = rest >> 5;         // 0..1
    const int ntb  = rest & 31;         // 0..31
    const int b    = b_lo + (b_hi << 3);
    const int nt   = ntb * WPB + w;

    const int n  = nt * 16 + col;
    const int mbase = z * MSEG;

    const uint4* amb = Am + (size_t)b * NTOK * 4;
    const float* sqb = sqf + (size_t)b * NTOK;

    // B-frags from interleaved layout (R13)
    const uint4 bh4 = amb[(size_t)nt*64 + ((quad & 1) * 16) + col];
    const uint4 bl4 = amb[(size_t)nt*64 + ((2 + (quad & 1)) * 16) + col];
    const bf16x8 Bhi = *(const bf16x8*)&bh4;
    const bf16x8 Blo = *(const bf16x8*)&bl4;

    const float sqn  = sqb[n];
    // ranking bias: d_true = (sqm - 2g) + sqn >= -1e-3 (approx err); +4 makes the
    // biased key strictly positive -> positive-float uint compare is monotone.
    const float bias = sqn + 4.0f;

    unsigned k0 = ~0u, k1 = ~0u, k2 = ~0u, k3 = ~0u;
    const int moff = quad * 4;
    const int tgbase = z * (MSEG / 16);   // global tile base for this half

#pragma unroll 2
    for (int t = 0; t < MSEG / 16; ++t) {
        // A-frag: contiguous 1 KB tile, lane l reads element l (coalesced)
        const uint4 af4 = amb[(size_t)(tgbase + t) * 64 + l];
        const bf16x8 Af = *(const bf16x8*)&af4;
        const float4 sq4 = *(const float4*)(sqb + mbase + t * 16 + moff);

        f32x4v acc = {0.0f, 0.0f, 0.0f, 0.0f};
        acc = __builtin_amdgcn_mfma_f32_16x16x32_bf16(Af, Bhi, acc, 0, 0, 0);
        acc = __builtin_amdgcn_mfma_f32_16x16x32_bf16(Af, Blo, acc, 0, 0, 0);

        const int mb = mbase + t * 16 + moff;
        const float sqa[4] = { sq4.x, sq4.y, sq4.z, sq4.w };
#pragma unroll
        for (int r = 0; r < 4; ++r) {
            // biased ranking distance (> 0): fma + add
            const float d = __fadd_rn(__fmaf_rn(-2.0f, acc[r], sqa[r]), bias);
            // key: truncate low 11 mantissa bits, pack global m (and_or)
            const unsigned key = (__float_as_uint(d) & 0xFFFFF800u) | (unsigned)(mb + r);
            // sorted-top-4 insert: min + 3x med3 (identical to streaming insert)
            const unsigned ok0 = k0, ok1 = k1, ok2 = k2;
            k0 = umin2(key, k0);
            k1 = med3u(key, ok0, k1);
            k2 = med3u(key, ok1, k2);
            k3 = med3u(key, ok2, k3);
        }
    }

    // dump 4 candidate indices per lane (decode global m from key)
    lds_ci[w][col][quad*4+0] = (int)(k0 & 2047u);
    lds_ci[w][col][quad*4+1] = (int)(k1 & 2047u);
    lds_ci[w][col][quad*4+2] = (int)(k2 & 2047u);
    lds_ci[w][col][quad*4+3] = (int)(k3 & 2047u);
    __syncthreads();

    // exact rescore: lane (col, quad) rescores candidates quad*4..+3 of n=col
    float xn[C_IN];
    {
        const float4* src = (const float4*)(xTf + ((size_t)b * NTOK + n) * C_IN);
#pragma unroll
        for (int j = 0; j < 4; ++j) {
            const float4 tq = src[j];
            xn[4*j+0] = tq.x; xn[4*j+1] = tq.y; xn[4*j+2] = tq.z; xn[4*j+3] = tq.w;
        }
    }
#pragma unroll
    for (int c = 0; c < 4; ++c) {
        const int cand = quad * 4 + c;
        const int mi = lds_ci[w][col][cand];
        const float4* xm4 = (const float4*)(xTf + ((size_t)b * NTOK + mi) * C_IN);
        const float4 a0 = xm4[0], a1 = xm4[1], a2 = xm4[2], a3 = xm4[3];
        float g = 0.0f;
        g = __fmaf_rn(xn[0],  a0.x, g); g = __fmaf_rn(xn[1],  a0.y, g);
        g = __fmaf_rn(xn[2],  a0.z, g); g = __fmaf_rn(xn[3],  a0.w, g);
        g = __fmaf_rn(xn[4],  a1.x, g); g = __fmaf_rn(xn[5],  a1.y, g);
        g = __fmaf_rn(xn[6],  a1.z, g); g = __fmaf_rn(xn[7],  a1.w, g);
        g = __fmaf_rn(xn[8],  a2.x, g); g = __fmaf_rn(xn[9],  a2.y, g);
        g = __fmaf_rn(xn[10], a2.z, g); g = __fmaf_rn(xn[11], a2.w, g);
        g = __fmaf_rn(xn[12], a3.x, g); g = __fmaf_rn(xn[13], a3.y, g);
        g = __fmaf_rn(xn[14], a3.z, g); g = __fmaf_rn(xn[15], a3.w, g);
        // exact (reference-rounded) distance
        lds_de[w][col][cand] = __fadd_rn(__fmaf_rn(-2.0f, g, sqn), sqb[mi]);
    }
    __syncthreads();

    // stable top-3 over 16 exact (d, idx): lexicographic, matches jax top_k ties
    if (l < 16) {
        float D0 = FLT_MAX, D1 = FLT_MAX, D2 = FLT_MAX;
        int   I0 = INT_MAX, I1 = INT_MAX, I2 = INT_MAX;
#pragma unroll
        for (int c = 0; c < 16; ++c) {
            const float d = lds_de[w][l][c];
            const int  ix = lds_ci[w][l][c];
            const bool b0 = (d < D0) || (d == D0 && ix < I0);
            const bool b1 = (d < D1) || (d == D1 && ix < I1);
            const bool b2 = (d < D2) || (d == D2 && ix < I2);
            const float oD0 = D0, oD1 = D1;
            const int   oI0 = I0, oI1 = I1;
            D0 = b0 ? d : D0;               I0 = b0 ? ix : I0;
            D1 = b0 ? oD0 : (b1 ? d : D1);  I1 = b0 ? oI0 : (b1 ? ix : I1);
            D2 = b1 ? oD1 : (b2 ? d : D2);  I2 = b1 ? oI1 : (b2 ? ix : I2);
        }
        // records: [((z*KNN + k)*BATCH + b)*NTOK + n]
        const size_t base = ((size_t)z * KNN * BATCH + b) * NTOK + nt * 16 + l;
        const size_t kstr = (size_t)BATCH * NTOK;
        pd[base + 0*kstr] = D0;  pi[base + 0*kstr] = I0;
        pd[base + 1*kstr] = D1;  pi[base + 1*kstr] = I1;
        pd[base + 2*kstr] = D2;  pi[base + 2*kstr] = I2;
    }
}

// Kernel 3: merge the 2 halves' exact top-3 (lexicographic on (d, m) == stable
// global top-3), gather 3 neighbor columns, conv epilogue. Same b-locality swizzle.
__global__ void __launch_bounds__(256) merge_conv_kernel(
    const float* __restrict__ xTf, const float* __restrict__ pd,
    const int* __restrict__ pi, const float* __restrict__ W,
    const float* __restrict__ bias, float* __restrict__ out)
{
    // decode swizzled block coords: wg = (b%8) + 8*((b/8)*8 + xc), 256 blocks
    const int wg   = blockIdx.x;        // 0..255
    const int b_lo = wg & 7;
    const int t2   = wg >> 3;           // 0..31
    const int b_hi = t2 >> 3;           // 0..3
    const int xc   = t2 & 7;            // 0..7
    const int b    = b_lo + (b_hi << 3);
    const int n    = xc * 256 + threadIdx.x;

    float D0 = FLT_MAX, D1 = FLT_MAX, D2 = FLT_MAX;
    int   I0 = INT_MAX, I1 = INT_MAX, I2 = INT_MAX;
    const size_t kstr = (size_t)BATCH * NTOK;
#pragma unroll
    for (int z = 0; z < ZH; ++z) {
        const size_t base = ((size_t)z * KNN * BATCH + b) * NTOK + n;
#pragma unroll
        for (int k = 0; k < KNN; ++k) {
            const float d = pd[base + (size_t)k * kstr];
            const int  ix = pi[base + (size_t)k * kstr];
            const bool b0 = (d < D0) || (d == D0 && ix < I0);
            const bool b1 = (d < D1) || (d == D1 && ix < I1);
            const bool b2 = (d < D2) || (d == D2 && ix < I2);
            const float oD0 = D0, oD1 = D1;
            const int   oI0 = I0, oI1 = I1;
            D0 = b0 ? d : D0;               I0 = b0 ? ix : I0;
            D1 = b0 ? oD0 : (b1 ? d : D1);  I1 = b0 ? oI0 : (b1 ? ix : I1);
            D2 = b1 ? oD1 : (b2 ? d : D2);  I2 = b1 ? oI1 : (b2 ? ix : I2);
        }
    }

    const float* xb = xTf + (size_t)b * NTOK * C_IN;
    float xg[KNN][C_IN];
    const int idx[KNN] = { I0, I1, I2 };
#pragma unroll
    for (int k = 0; k < KNN; ++k) {
        const float4* src = (const float4*)(xb + (size_t)idx[k] * C_IN);
#pragma unroll
        for (int j = 0; j < 4; ++j) {
            const float4 t = src[j];
            xg[k][4*j+0] = t.x; xg[k][4*j+1] = t.y;
            xg[k][4*j+2] = t.z; xg[k][4*j+3] = t.w;
        }
    }

#pragma unroll
    for (int o = 0; o < C_OUT; ++o) {
        float acc = bias[o];
#pragma unroll
        for (int c = 0; c < C_IN; ++c) {
#pragma unroll
            for (int k = 0; k < KNN; ++k)
                acc = __fmaf_rn(W[(o * C_IN + c) * KNN + k], xg[k][c], acc);
        }
        out[((size_t)b * C_OUT + o) * NTOK + n] = acc;
    }
}

extern "C" void kernel_launch(void* const* d_in, const int* in_sizes, int n_in,
                              void* d_out, int out_size, void* d_ws, size_t ws_size,
                              hipStream_t stream) {
    const float* x    = (const float*)d_in[0];
    const float* W    = (const float*)d_in[1];
    const float* bias = (const float*)d_in[2];
    float* out = (float*)d_out;

    char* ws = (char*)d_ws;
    const size_t BN = (size_t)BATCH * NTOK;
    uint4* Am  = (uint4*)ws;                       // 4 MB
    float* sqf = (float*)(ws + BN * 64);           // 256 KB
    float* xTf = (float*)(ws + BN * 68);           // 4 MB
    float* pd  = (float*)(ws + BN * 68 + BN * 64); // ZH*KNN*BN*4 = 1.5 MB
    int*   pi  = (int*)  (ws + BN * 68 + BN * 64 + (size_t)ZH * KNN * BN * 4);

    dim3 grid1(NTOK / 256, BATCH);
    prep_kernel<<<grid1, 256, 0, stream>>>(x, xTf, sqf, Am);

    // 2048 blocks, 1-D, XCD-swizzled
    knn_scan_kernel<<<dim3(BATCH * (NTOK / (16 * WPB)) * ZH), 256, 0, stream>>>(Am, sqf, xTf, pd, pi);

    // 256 blocks, 1-D, XCD-swizzled
    merge_conv_kernel<<<dim3(BATCH * (NTOK / 256)), 256, 0, stream>>>(xTf, pd, pi, W, bias, out);
}